// Round 2
// baseline (496.199 us; speedup 1.0000x reference)
//
#include <hip/hip_runtime.h>
#include <stdint.h>

// bf16 flash-attention forward, causal, B=2 H=16 T=4096 D=128, fp32 in/out.
// S^T = K*Q^T (q on lane&31 for softmax), O^T = V^T*P^T (alpha per-lane).
// R7 = R6 (unverified: GPU unavailable 2 rounds) + T5 s_setprio around MFMA.
//  (1) P NEVER TOUCHES LDS. The MFMA C-layout -> B-operand mismatch is
//      absorbed by permuting Vt_lds's kv-column order: V[kv] is stored at
//      column sigma(kv) = kv with bits 2,3 swapped. MFMA sums over k in any
//      order as long as the P fragment and V^T fragment agree on the same
//      kv permutation; with sigma, pf[c][j] = s[c>>1][(c&1)*8 + j] — eight
//      CONSECUTIVE own registers. Removes 8 ds_write_b64 + 4 ds_read_b128 +
//      the lgkm dependency per tile, and 18 KB LDS (Pq_lds deleted).
//  (2) T13 defer-max: skip O/l rescale when __all(mloc - m_run <= 8) (log2
//      units since qscale folds log2e). P <= 2^8 = 256, bf16-safe. All-masked
//      lanes impossible: kbase-qw ≡ 0 mod 32, so the p=exp2(0)=1 hazard never
//      occurs (same invariant the verified R5 relied on).
//  (3) T5: setprio(1) around both MFMA clusters (+4-7% attn, m191).

typedef __bf16 bf16x8 __attribute__((ext_vector_type(8)));
typedef float f32x16 __attribute__((ext_vector_type(16)));
typedef unsigned short u16x8 __attribute__((ext_vector_type(8)));
typedef unsigned int u32x2 __attribute__((ext_vector_type(2)));

#define T_SEQ 4096
#define D_HEAD 128
#define BQ 128          // q rows per block (4 waves x 32)
#define BK 64           // kv rows per tile
#define KSTR 136        // K_lds row stride in shorts (128 + 8 pad)
#define VSTR 72         // Vt_lds row stride in shorts (64 + 8 pad)

// pack two f32 -> bf16x2 (round-half-up: +0x8000, take hi16). 3 VALU / 2 elem.
__device__ __forceinline__ unsigned int pack_bf2(float a, float b) {
    unsigned int ua = __builtin_bit_cast(unsigned int, a) + 0x8000u;
    unsigned int ub = __builtin_bit_cast(unsigned int, b) + 0x8000u;
    return __builtin_amdgcn_perm(ub, ua, 0x07060302);  // [ub.hi16 | ua.hi16]
}

__global__ __launch_bounds__(256, 2) void fa_fwd(
    const float* __restrict__ Qg, const float* __restrict__ Kg,
    const float* __restrict__ Vg, float* __restrict__ Og)
{
    __shared__ unsigned short K_lds[BK * KSTR];        // K[kv][d]          17408 B
    __shared__ unsigned short Vt_lds[D_HEAD * VSTR];   // V^T[d][sigma(kv)] 18432 B

    const int tid  = threadIdx.x;
    const int w    = tid >> 6;      // wave 0..3
    const int lane = tid & 63;
    const int r    = lane & 31;     // n-index within MFMA tiles
    const int h    = lane >> 5;     // half-wave

    const int qt = (int)(gridDim.x - 1 - blockIdx.x); // big tiles first
    const int bh = blockIdx.y;
    const int q0 = qt * BQ;

    const float* Qb = Qg + (size_t)bh * T_SEQ * D_HEAD;
    const float* Kb = Kg + (size_t)bh * T_SEQ * D_HEAD;
    const float* Vb = Vg + (size_t)bh * T_SEQ * D_HEAD;
    float*       Ob = Og + (size_t)bh * T_SEQ * D_HEAD;

    const int qw      = q0 + 32 * w;
    const int q_lane  = qw + r;
    const int qw_last = qw + 31;

    // ---- Q fragments (B-operand), pre-scaled by 1/sqrt(D)*log2(e)
    const float qscale = 0.08838834764831845f * 1.4426950408889634f;
    bf16x8 qf[8];
#pragma unroll
    for (int c = 0; c < 8; ++c) {
        const float* src = Qb + (size_t)q_lane * D_HEAD + c * 16 + h * 8;
        float4 f0 = *(const float4*)(src);
        float4 f1 = *(const float4*)(src + 4);
        unsigned int u0 = pack_bf2(f0.x * qscale, f0.y * qscale);
        unsigned int u1 = pack_bf2(f0.z * qscale, f0.w * qscale);
        unsigned int u2 = pack_bf2(f1.x * qscale, f1.y * qscale);
        unsigned int u3 = pack_bf2(f1.z * qscale, f1.w * qscale);
        u16x8 u = { (unsigned short)u0, (unsigned short)(u0 >> 16),
                    (unsigned short)u1, (unsigned short)(u1 >> 16),
                    (unsigned short)u2, (unsigned short)(u2 >> 16),
                    (unsigned short)u3, (unsigned short)(u3 >> 16) };
        qf[c] = __builtin_bit_cast(bf16x8, u);
    }

    f32x16 o[4];
#pragma unroll
    for (int mt = 0; mt < 4; ++mt) o[mt] = (f32x16)0.0f;
    float m_run = -1e30f, l_run = 0.0f;

    // staging geometry
    const int krow = tid >> 5;            // 0..7
    const int kd0  = (tid & 31) * 4;
    const int vd   = tid & 127;
    const int vhh  = tid >> 7;            // 0,1

    // ---- prefetch registers (tile kt+1 in flight during compute of kt)
    float4 kpre[8];
    float  vpre[8][4];

    // preload tile 0
#pragma unroll
    for (int p = 0; p < 8; ++p)
        kpre[p] = *(const float4*)(Kb + (size_t)(p * 8 + krow) * D_HEAD + kd0);
#pragma unroll
    for (int p = 0; p < 8; ++p) {
        const int kv0 = p * 8 + vhh * 4;
        const float* vs = Vb + (size_t)kv0 * D_HEAD + vd;
        vpre[p][0] = vs[0];
        vpre[p][1] = vs[D_HEAD];
        vpre[p][2] = vs[2 * D_HEAD];
        vpre[p][3] = vs[3 * D_HEAD];
    }

    const int ntiles = 2 * qt + 2;
    for (int kt = 0; kt < ntiles; ++kt) {
        const int kbase = kt * BK;
        __syncthreads();   // prev compute done with LDS; drains prefetch vmcnt

        // ---- write prefetched tile into LDS (pack to bf16)
#pragma unroll
        for (int p = 0; p < 8; ++p) {
            u32x2 u;
            u[0] = pack_bf2(kpre[p].x, kpre[p].y);
            u[1] = pack_bf2(kpre[p].z, kpre[p].w);
            *(u32x2*)&K_lds[(p * 8 + krow) * KSTR + kd0] = u;
        }
        // V columns permuted: kv = 8p + 4*vhh + i  ->  col = sigma(kv)
        // (swap bits 2,3):    col = 16*(p>>1) + 8*vhh + 4*(p&1) + i
#pragma unroll
        for (int p = 0; p < 8; ++p) {
            u32x2 u;
            u[0] = pack_bf2(vpre[p][0], vpre[p][1]);
            u[1] = pack_bf2(vpre[p][2], vpre[p][3]);
            const int col = (p >> 1) * 16 + vhh * 8 + (p & 1) * 4;
            *(u32x2*)&Vt_lds[vd * VSTR + col] = u;
        }
        __syncthreads();

        // ---- issue next tile's global loads; they fly during compute below
        if (kt + 1 < ntiles) {
            const int nb = kbase + BK;
#pragma unroll
            for (int p = 0; p < 8; ++p)
                kpre[p] = *(const float4*)(Kb + (size_t)(nb + p * 8 + krow) * D_HEAD + kd0);
#pragma unroll
            for (int p = 0; p < 8; ++p) {
                const int kv0 = nb + p * 8 + vhh * 4;
                const float* vs = Vb + (size_t)kv0 * D_HEAD + vd;
                vpre[p][0] = vs[0];
                vpre[p][1] = vs[D_HEAD];
                vpre[p][2] = vs[2 * D_HEAD];
                vpre[p][3] = vs[3 * D_HEAD];
            }
        }

        if (kbase > qw_last) continue;   // wave-uniform; barriers stay aligned

        // ---- S^T = K * Q^T : two 32-kv m-tiles
        f32x16 s[2];
        s[0] = (f32x16)0.0f; s[1] = (f32x16)0.0f;
        __builtin_amdgcn_s_setprio(1);
#pragma unroll
        for (int t = 0; t < 2; ++t) {
#pragma unroll
            for (int c = 0; c < 8; ++c) {
                u16x8 raw = *(const u16x8*)&K_lds[(t * 32 + r) * KSTR + c * 16 + h * 8];
                bf16x8 a = __builtin_bit_cast(bf16x8, raw);
                s[t] = __builtin_amdgcn_mfma_f32_32x32x16_bf16(a, qf[c], s[t], 0, 0, 0);
            }
        }
        __builtin_amdgcn_s_setprio(0);

        // ---- causal mask (vs wave's FIRST q)
        if (kbase + BK - 1 > qw) {
#pragma unroll
            for (int t = 0; t < 2; ++t)
#pragma unroll
                for (int g = 0; g < 16; ++g) {
                    int kv = kbase + t * 32 + (g & 3) + 8 * (g >> 2) + 4 * h;
                    if (kv > q_lane) s[t][g] = -1e30f;
                }
        }

        // ---- online softmax (per q = lane&31; combine two half-waves)
        float mloc = -1e30f;
#pragma unroll
        for (int t = 0; t < 2; ++t)
#pragma unroll
            for (int g = 0; g < 16; ++g) mloc = fmaxf(mloc, s[t][g]);
        mloc = fmaxf(mloc, __shfl_xor(mloc, 32, 64));

        // T13 defer-max: only rescale when some row's max grew by > 8 (log2).
        if (!__all(mloc - m_run <= 8.0f)) {
            const float m_new = fmaxf(m_run, mloc);
            const float alpha = __builtin_amdgcn_exp2f(m_run - m_new);
            l_run *= alpha;
#pragma unroll
            for (int mt = 0; mt < 4; ++mt)
#pragma unroll
                for (int g = 0; g < 16; ++g) o[mt][g] *= alpha;
            m_run = m_new;
        }

        float rsum = 0.0f;
#pragma unroll
        for (int t = 0; t < 2; ++t)
#pragma unroll
            for (int g = 0; g < 16; ++g) {
                float p = __builtin_amdgcn_exp2f(s[t][g] - m_run);
                s[t][g] = p;
                rsum += p;
            }
        rsum += __shfl_xor(rsum, 32, 64);
        l_run += rsum;

        // ---- P^T B-fragments DIRECTLY from registers.
        // pf[c][j] = p[c>>1][(c&1)*8 + j] holds kv = 16c + 8*(j>>2) + 4h + (j&3)
        // = sigma(16c + 8h + j): matches Vt_lds's permuted column at the same
        // (c,h,j) A-slot, so the MFMA k-sum pairs identical kv on both sides.
        bf16x8 pf[4];
#pragma unroll
        for (int c = 0; c < 4; ++c) {
            const int t  = c >> 1;
            const int g0 = (c & 1) * 8;
            unsigned int u0 = pack_bf2(s[t][g0 + 0], s[t][g0 + 1]);
            unsigned int u1 = pack_bf2(s[t][g0 + 2], s[t][g0 + 3]);
            unsigned int u2 = pack_bf2(s[t][g0 + 4], s[t][g0 + 5]);
            unsigned int u3 = pack_bf2(s[t][g0 + 6], s[t][g0 + 7]);
            u16x8 u = { (unsigned short)u0, (unsigned short)(u0 >> 16),
                        (unsigned short)u1, (unsigned short)(u1 >> 16),
                        (unsigned short)u2, (unsigned short)(u2 >> 16),
                        (unsigned short)u3, (unsigned short)(u3 >> 16) };
            pf[c] = __builtin_bit_cast(bf16x8, u);
        }

        // ---- O^T += V^T * P^T
        __builtin_amdgcn_s_setprio(1);
#pragma unroll
        for (int mt = 0; mt < 4; ++mt) {
#pragma unroll
            for (int c = 0; c < 4; ++c) {
                u16x8 raw = *(const u16x8*)&Vt_lds[(mt * 32 + r) * VSTR + c * 16 + h * 8];
                bf16x8 a = __builtin_bit_cast(bf16x8, raw);
                o[mt] = __builtin_amdgcn_mfma_f32_32x32x16_bf16(a, pf[c], o[mt], 0, 0, 0);
            }
        }
        __builtin_amdgcn_s_setprio(0);
    }

    // ---- epilogue: O[q][d] = O^T / l
    const float inv = 1.0f / l_run;
#pragma unroll
    for (int mt = 0; mt < 4; ++mt)
#pragma unroll
        for (int g4 = 0; g4 < 4; ++g4) {
            float4 vv;
            vv.x = o[mt][g4 * 4 + 0] * inv;
            vv.y = o[mt][g4 * 4 + 1] * inv;
            vv.z = o[mt][g4 * 4 + 2] * inv;
            vv.w = o[mt][g4 * 4 + 3] * inv;
            const int dd = mt * 32 + g4 * 8 + h * 4;
            *(float4*)(Ob + (size_t)q_lane * D_HEAD + dd) = vv;
        }
}

extern "C" void kernel_launch(void* const* d_in, const int* in_sizes, int n_in,
                              void* d_out, int out_size, void* d_ws, size_t ws_size,
                              hipStream_t stream) {
    const float* Q = (const float*)d_in[0];
    const float* K = (const float*)d_in[1];
    const float* V = (const float*)d_in[2];
    float* O = (float*)d_out;
    const int BH = in_sizes[0] / (T_SEQ * D_HEAD);   // 32
    dim3 grid(T_SEQ / BQ, BH, 1);
    fa_fwd<<<grid, 256, 0, stream>>>(Q, K, V, O);
}

// Round 3
// 422.685 us; speedup vs baseline: 1.1739x; 1.1739x over previous
//
#include <hip/hip_runtime.h>
#include <stdint.h>

// bf16 flash-attention forward, causal, B=2 H=16 T=4096 D=128, fp32 in/out.
// S^T = K*Q^T (q on lane&31 for softmax), O^T = V^T*P^T (alpha per-lane).
// R8 = R7 body (verified: P-in-register via sigma-permuted Vt, defer-max,
// setprio, register prefetch) wrapped in CAUSAL PAIRING for load balance.
//
// R7 counters: MfmaUtil 14.7 / VALUBusy 22.9 / Occupancy 11.8 / HBM 17% —
// all pipes idle; wall set by heavy-qt blocks running ~1 block/CU in the
// tail (causal triangle = 32:1 work spread across blocks).
// R8: block x in [0,16) processes qt = 31-x THEN qt = x: every block does
// exactly 66 tile-units. 512 blocks = 2/CU resident, uniform finish, no
// serial tail. Body is untouched (same barriers per half; registers reused
// between halves).

typedef __bf16 bf16x8 __attribute__((ext_vector_type(8)));
typedef float f32x16 __attribute__((ext_vector_type(16)));
typedef unsigned short u16x8 __attribute__((ext_vector_type(8)));
typedef unsigned int u32x2 __attribute__((ext_vector_type(2)));

#define T_SEQ 4096
#define D_HEAD 128
#define BQ 128          // q rows per block-half (4 waves x 32)
#define NQT (T_SEQ / BQ) // 32 q-tiles
#define BK 64           // kv rows per tile
#define KSTR 136        // K_lds row stride in shorts (128 + 8 pad)
#define VSTR 72         // Vt_lds row stride in shorts (64 + 8 pad)

// pack two f32 -> bf16x2 (round-half-up: +0x8000, take hi16). 3 VALU / 2 elem.
__device__ __forceinline__ unsigned int pack_bf2(float a, float b) {
    unsigned int ua = __builtin_bit_cast(unsigned int, a) + 0x8000u;
    unsigned int ub = __builtin_bit_cast(unsigned int, b) + 0x8000u;
    return __builtin_amdgcn_perm(ub, ua, 0x07060302);  // [ub.hi16 | ua.hi16]
}

__global__ __launch_bounds__(256, 2) void fa_fwd(
    const float* __restrict__ Qg, const float* __restrict__ Kg,
    const float* __restrict__ Vg, float* __restrict__ Og)
{
    __shared__ unsigned short K_lds[BK * KSTR];        // K[kv][d]          17408 B
    __shared__ unsigned short Vt_lds[D_HEAD * VSTR];   // V^T[d][sigma(kv)] 18432 B

    const int tid  = threadIdx.x;
    const int w    = tid >> 6;      // wave 0..3
    const int lane = tid & 63;
    const int r    = lane & 31;     // n-index within MFMA tiles
    const int h    = lane >> 5;     // half-wave

    const int pair = (int)blockIdx.x;   // 0..15
    const int bh   = blockIdx.y;

    const float* Qb = Qg + (size_t)bh * T_SEQ * D_HEAD;
    const float* Kb = Kg + (size_t)bh * T_SEQ * D_HEAD;
    const float* Vb = Vg + (size_t)bh * T_SEQ * D_HEAD;
    float*       Ob = Og + (size_t)bh * T_SEQ * D_HEAD;

    // staging geometry (half-invariant)
    const int krow = tid >> 5;            // 0..7
    const int kd0  = (tid & 31) * 4;
    const int vd   = tid & 127;
    const int vhh  = tid >> 7;            // 0,1

    const float qscale = 0.08838834764831845f * 1.4426950408889634f;

    for (int half = 0; half < 2; ++half) {
        const int qt = (half == 0) ? (NQT - 1 - pair) : pair;  // heavy first
        const int q0 = qt * BQ;

        const int qw      = q0 + 32 * w;
        const int q_lane  = qw + r;
        const int qw_last = qw + 31;

        // ---- Q fragments (B-operand), pre-scaled by 1/sqrt(D)*log2(e)
        bf16x8 qf[8];
#pragma unroll
        for (int c = 0; c < 8; ++c) {
            const float* src = Qb + (size_t)q_lane * D_HEAD + c * 16 + h * 8;
            float4 f0 = *(const float4*)(src);
            float4 f1 = *(const float4*)(src + 4);
            unsigned int u0 = pack_bf2(f0.x * qscale, f0.y * qscale);
            unsigned int u1 = pack_bf2(f0.z * qscale, f0.w * qscale);
            unsigned int u2 = pack_bf2(f1.x * qscale, f1.y * qscale);
            unsigned int u3 = pack_bf2(f1.z * qscale, f1.w * qscale);
            u16x8 u = { (unsigned short)u0, (unsigned short)(u0 >> 16),
                        (unsigned short)u1, (unsigned short)(u1 >> 16),
                        (unsigned short)u2, (unsigned short)(u2 >> 16),
                        (unsigned short)u3, (unsigned short)(u3 >> 16) };
            qf[c] = __builtin_bit_cast(bf16x8, u);
        }

        f32x16 o[4];
#pragma unroll
        for (int mt = 0; mt < 4; ++mt) o[mt] = (f32x16)0.0f;
        float m_run = -1e30f, l_run = 0.0f;

        // ---- prefetch registers (tile kt+1 in flight during compute of kt)
        float4 kpre[8];
        float  vpre[8][4];

        // preload tile 0
#pragma unroll
        for (int p = 0; p < 8; ++p)
            kpre[p] = *(const float4*)(Kb + (size_t)(p * 8 + krow) * D_HEAD + kd0);
#pragma unroll
        for (int p = 0; p < 8; ++p) {
            const int kv0 = p * 8 + vhh * 4;
            const float* vs = Vb + (size_t)kv0 * D_HEAD + vd;
            vpre[p][0] = vs[0];
            vpre[p][1] = vs[D_HEAD];
            vpre[p][2] = vs[2 * D_HEAD];
            vpre[p][3] = vs[3 * D_HEAD];
        }

        const int ntiles = 2 * qt + 2;
        for (int kt = 0; kt < ntiles; ++kt) {
            const int kbase = kt * BK;
            __syncthreads();   // prev compute done with LDS; drains prefetch vmcnt

            // ---- write prefetched tile into LDS (pack to bf16)
#pragma unroll
            for (int p = 0; p < 8; ++p) {
                u32x2 u;
                u[0] = pack_bf2(kpre[p].x, kpre[p].y);
                u[1] = pack_bf2(kpre[p].z, kpre[p].w);
                *(u32x2*)&K_lds[(p * 8 + krow) * KSTR + kd0] = u;
            }
            // V columns permuted: kv = 8p + 4*vhh + i  ->  col = sigma(kv)
            // (swap bits 2,3):    col = 16*(p>>1) + 8*vhh + 4*(p&1) + i
#pragma unroll
            for (int p = 0; p < 8; ++p) {
                u32x2 u;
                u[0] = pack_bf2(vpre[p][0], vpre[p][1]);
                u[1] = pack_bf2(vpre[p][2], vpre[p][3]);
                const int col = (p >> 1) * 16 + vhh * 8 + (p & 1) * 4;
                *(u32x2*)&Vt_lds[vd * VSTR + col] = u;
            }
            __syncthreads();

            // ---- issue next tile's global loads; they fly during compute below
            if (kt + 1 < ntiles) {
                const int nb = kbase + BK;
#pragma unroll
                for (int p = 0; p < 8; ++p)
                    kpre[p] = *(const float4*)(Kb + (size_t)(nb + p * 8 + krow) * D_HEAD + kd0);
#pragma unroll
                for (int p = 0; p < 8; ++p) {
                    const int kv0 = nb + p * 8 + vhh * 4;
                    const float* vs = Vb + (size_t)kv0 * D_HEAD + vd;
                    vpre[p][0] = vs[0];
                    vpre[p][1] = vs[D_HEAD];
                    vpre[p][2] = vs[2 * D_HEAD];
                    vpre[p][3] = vs[3 * D_HEAD];
                }
            }

            if (kbase > qw_last) continue;   // wave-uniform; barriers stay aligned

            // ---- S^T = K * Q^T : two 32-kv m-tiles
            f32x16 s[2];
            s[0] = (f32x16)0.0f; s[1] = (f32x16)0.0f;
            __builtin_amdgcn_s_setprio(1);
#pragma unroll
            for (int t = 0; t < 2; ++t) {
#pragma unroll
                for (int c = 0; c < 8; ++c) {
                    u16x8 raw = *(const u16x8*)&K_lds[(t * 32 + r) * KSTR + c * 16 + h * 8];
                    bf16x8 a = __builtin_bit_cast(bf16x8, raw);
                    s[t] = __builtin_amdgcn_mfma_f32_32x32x16_bf16(a, qf[c], s[t], 0, 0, 0);
                }
            }
            __builtin_amdgcn_s_setprio(0);

            // ---- causal mask (vs wave's FIRST q)
            if (kbase + BK - 1 > qw) {
#pragma unroll
                for (int t = 0; t < 2; ++t)
#pragma unroll
                    for (int g = 0; g < 16; ++g) {
                        int kv = kbase + t * 32 + (g & 3) + 8 * (g >> 2) + 4 * h;
                        if (kv > q_lane) s[t][g] = -1e30f;
                    }
            }

            // ---- online softmax (per q = lane&31; combine two half-waves)
            float mloc = -1e30f;
#pragma unroll
            for (int t = 0; t < 2; ++t)
#pragma unroll
                for (int g = 0; g < 16; ++g) mloc = fmaxf(mloc, s[t][g]);
            mloc = fmaxf(mloc, __shfl_xor(mloc, 32, 64));

            // T13 defer-max: only rescale when some row's max grew by > 8 (log2).
            if (!__all(mloc - m_run <= 8.0f)) {
                const float m_new = fmaxf(m_run, mloc);
                const float alpha = __builtin_amdgcn_exp2f(m_run - m_new);
                l_run *= alpha;
#pragma unroll
                for (int mt = 0; mt < 4; ++mt)
#pragma unroll
                    for (int g = 0; g < 16; ++g) o[mt][g] *= alpha;
                m_run = m_new;
            }

            float rsum = 0.0f;
#pragma unroll
            for (int t = 0; t < 2; ++t)
#pragma unroll
                for (int g = 0; g < 16; ++g) {
                    float p = __builtin_amdgcn_exp2f(s[t][g] - m_run);
                    s[t][g] = p;
                    rsum += p;
                }
            rsum += __shfl_xor(rsum, 32, 64);
            l_run += rsum;

            // ---- P^T B-fragments DIRECTLY from registers.
            // pf[c][j] = p[c>>1][(c&1)*8 + j] holds kv = 16c + 8*(j>>2) + 4h + (j&3)
            // = sigma(16c + 8h + j): matches Vt_lds's permuted column at the same
            // (c,h,j) A-slot, so the MFMA k-sum pairs identical kv on both sides.
            bf16x8 pf[4];
#pragma unroll
            for (int c = 0; c < 4; ++c) {
                const int t  = c >> 1;
                const int g0 = (c & 1) * 8;
                unsigned int u0 = pack_bf2(s[t][g0 + 0], s[t][g0 + 1]);
                unsigned int u1 = pack_bf2(s[t][g0 + 2], s[t][g0 + 3]);
                unsigned int u2 = pack_bf2(s[t][g0 + 4], s[t][g0 + 5]);
                unsigned int u3 = pack_bf2(s[t][g0 + 6], s[t][g0 + 7]);
                u16x8 u = { (unsigned short)u0, (unsigned short)(u0 >> 16),
                            (unsigned short)u1, (unsigned short)(u1 >> 16),
                            (unsigned short)u2, (unsigned short)(u2 >> 16),
                            (unsigned short)u3, (unsigned short)(u3 >> 16) };
                pf[c] = __builtin_bit_cast(bf16x8, u);
            }

            // ---- O^T += V^T * P^T
            __builtin_amdgcn_s_setprio(1);
#pragma unroll
            for (int mt = 0; mt < 4; ++mt) {
#pragma unroll
                for (int c = 0; c < 4; ++c) {
                    u16x8 raw = *(const u16x8*)&Vt_lds[(mt * 32 + r) * VSTR + c * 16 + h * 8];
                    bf16x8 a = __builtin_bit_cast(bf16x8, raw);
                    o[mt] = __builtin_amdgcn_mfma_f32_32x32x16_bf16(a, pf[c], o[mt], 0, 0, 0);
                }
            }
            __builtin_amdgcn_s_setprio(0);
        }

        // ---- epilogue: O[q][d] = O^T / l
        const float inv = 1.0f / l_run;
#pragma unroll
        for (int mt = 0; mt < 4; ++mt)
#pragma unroll
            for (int g4 = 0; g4 < 4; ++g4) {
                float4 vv;
                vv.x = o[mt][g4 * 4 + 0] * inv;
                vv.y = o[mt][g4 * 4 + 1] * inv;
                vv.z = o[mt][g4 * 4 + 2] * inv;
                vv.w = o[mt][g4 * 4 + 3] * inv;
                const int dd = mt * 32 + g4 * 8 + h * 4;
                *(float4*)(Ob + (size_t)q_lane * D_HEAD + dd) = vv;
            }

        __syncthreads();   // LDS safe before next half restages
    }
}

extern "C" void kernel_launch(void* const* d_in, const int* in_sizes, int n_in,
                              void* d_out, int out_size, void* d_ws, size_t ws_size,
                              hipStream_t stream) {
    const float* Q = (const float*)d_in[0];
    const float* K = (const float*)d_in[1];
    const float* V = (const float*)d_in[2];
    float* O = (float*)d_out;
    const int BH = in_sizes[0] / (T_SEQ * D_HEAD);   // 32
    dim3 grid(NQT / 2, BH, 1);                        // 16 x 32 = 512 blocks
    fa_fwd<<<grid, 256, 0, stream>>>(Q, K, V, O);
}